// Round 12
// baseline (196.197 us; speedup 1.0000x reference)
//
#include <hip/hip_runtime.h>
#include <math.h>

#define BB 32
#define DD 256
#define KK 2048
#define HW 1024
#define CHW (DD*HW)
#define NN (BB*HW)         // 32768 rows
#define BETA 0.25f
#define RROWS 16
#define NCAND 8
#define BIAS 0.125f

typedef __attribute__((ext_vector_type(8))) short short8v;   // 8 bf16 (4 VGPR)
typedef __attribute__((ext_vector_type(4))) float f32x4;

typedef const __attribute__((address_space(1))) void gv_t;
typedef __attribute__((address_space(3))) void lv_t;

__device__ __forceinline__ void gl_lds16(const void* g, void* l) {
    // LDS dest = wave-uniform base (+ lane*16 by HW); global src = per-lane addr
    __builtin_amdgcn_global_load_lds((gv_t*)g, (lv_t*)l, 16, 0, 0);
}

__device__ __forceinline__ unsigned bfr(float f) {           // fp32 -> bf16 RNE
    unsigned u = __float_as_uint(f);
    return (u + 0x7FFFu + ((u >> 16) & 1u)) >> 16;
}
__device__ __forceinline__ unsigned bfpack(float lo, float hi) {
    return bfr(lo) | (bfr(hi) << 16);
}

#define BARRIER() do { asm volatile("" ::: "memory"); \
                       __builtin_amdgcn_s_barrier();  \
                       asm volatile("" ::: "memory"); } while (0)

// ---- prep: blocks 0..255 convert E->bf16 tiled; blocks 256..263 compute C
//      (C-part stages E rows through LDS coalesced; np-pairwise bitwise) ----
__global__ __launch_bounds__(256) void k_prep(const float* __restrict__ E,
                                              uint4* __restrict__ EbfT,
                                              float* __restrict__ Cref,
                                              float* __restrict__ Ckey) {
    int bid = blockIdx.x;
    if (bid < 256) {
        int u = bid * 256 + threadIdx.x;                 // 0..65535
        int code = u & 63, kc = (u >> 6) & 3, c = (u >> 8) & 7, t = u >> 11;
        int k = t * 64 + code;
        const float* s = E + ((size_t)k * DD + c * 32 + kc * 8);
        float4 f0 = *reinterpret_cast<const float4*>(s);
        float4 f1 = *reinterpret_cast<const float4*>(s + 4);
        uint4 o;
        o.x = bfpack(f0.x, f0.y); o.y = bfpack(f0.z, f0.w);
        o.z = bfpack(f1.x, f1.y); o.w = bfpack(f1.z, f1.w);
        EbfT[u] = o;
    } else {
        __shared__ float Ech[32][DD + 1];
        const int tid = threadIdx.x;
        const int kbase = (bid - 256) * 256;
        for (int cc = 0; cc < 8; ++cc) {
            __syncthreads();
            // stage rows kbase+cc*32 .. +31, coalesced (lanes = consecutive d)
            for (int i = 0; i < 32; ++i) {
                int idx = tid + i * 256;                 // 0..8191
                int row = idx >> 8, d = idx & 255;
                Ech[row][d] = E[(size_t)(kbase + cc * 32 + row) * DD + d];
            }
            __syncthreads();
            if (tid < 32) {
                const float* e = &Ech[tid][0];
                float res;
                {
#pragma clang fp contract(off)
                    float r0[8], r1[8];
                    #pragma unroll
                    for (int j = 0; j < 8; ++j) { float t2 = e[j];       r0[j] = t2 * t2; }
                    #pragma unroll
                    for (int j = 0; j < 8; ++j) { float t2 = e[128 + j]; r1[j] = t2 * t2; }
                    for (int i = 8; i < 128; i += 8) {
                        #pragma unroll
                        for (int j = 0; j < 8; ++j) { float t2 = e[i + j];       r0[j] += t2 * t2; }
                        #pragma unroll
                        for (int j = 0; j < 8; ++j) { float t2 = e[128 + i + j]; r1[j] += t2 * t2; }
                    }
                    float lo = ((r0[0]+r0[1])+(r0[2]+r0[3]))+((r0[4]+r0[5])+(r0[6]+r0[7]));
                    float hi = ((r1[0]+r1[1])+(r1[2]+r1[3]))+((r1[4]+r1[5])+(r1[6]+r1[7]));
                    res = lo + hi;
                }
                int k = kbase + cc * 32 + tid;
                Cref[k] = res;
                Ckey[k] = res + BIAS;
            }
        }
    }
}

// ---- MFMA screen v9: 512 thr = 8 waves (2 row-grp x 32 rows, 4 code-grp x 16),
//      64 rows/block, all 32 tiles, grid 512 (2 blocks/CU, 4 waves/SIMD).
//      A = 64 VGPR in regs; E LDS dbuf + counted vmcnt(4). ----
__global__ __launch_bounds__(512, 4) void k_screen(
        const float* __restrict__ X, const uint4* __restrict__ EbfT,
        const float* __restrict__ Ckey, uint4* __restrict__ ck)
{
    __shared__ __align__(1024) char lds[73728];   // 2x32KB E dbuf | 8KB ckl

    const int tid = threadIdx.x;
    const int w = tid >> 6;              // 0..7
    const int rg = w >> 2;               // 0..1 row group (32 rows each)
    const int cg = w & 3;                // 0..3 code group (16 codes each)
    const int lane = tid & 63;
    const int lid = lane & 15, kc = lane >> 4;
    const int nb = blockIdx.x * 64;
    const int b = nb >> 10;              // 64 | 1024 -> single b per block
    const int hw0 = nb & 1023;

    float* ckl = (float*)(lds + 65536);
    float ckg0 = Ckey[tid];
    float ckg1 = Ckey[tid + 512];
    float ckg2 = Ckey[tid + 1024];
    float ckg3 = Ckey[tid + 1536];

    // ---- A: rows hw0+rg*32+rt*16+lid, d = c*32+kc*8+j  (64 VGPR) ----
    short8v a[8][2];
    {
        const float* xb = X + (size_t)b * CHW + (hw0 + rg * 32 + lid);
        #pragma unroll
        for (int c = 0; c < 8; ++c)
            #pragma unroll
            for (int rt = 0; rt < 2; ++rt) {
                const float* pp = xb + rt * 16 + (size_t)(c * 32 + kc * 8) * HW;
                float f[8];
                #pragma unroll
                for (int j = 0; j < 8; ++j) f[j] = pp[(size_t)j * HW];
                uint4 v;
                v.x = bfpack(f[0], f[1]); v.y = bfpack(f[2], f[3]);
                v.z = bfpack(f[4], f[5]); v.w = bfpack(f[6], f[7]);
                a[c][rt] = *reinterpret_cast<short8v*>(&v);
            }
    }
    ckl[tid] = ckg0; ckl[tid + 512] = ckg1;
    ckl[tid + 1024] = ckg2; ckl[tid + 1536] = ckg3;

    auto stage = [&](int t, int p) {     // 8 waves x 4 insts x 1KB = 32KB tile
        const uint4* src = EbfT + ((size_t)t * 2048 + w * 256 + lane);
        char* dst = lds + p * 32768 + (w * 256) * 16;
        #pragma unroll
        for (int i = 0; i < 4; ++i)
            gl_lds16(src + i * 64, dst + i * 1024);
    };
    stage(0, 0);
    stage(1, 1);
    asm volatile("s_waitcnt vmcnt(0) lgkmcnt(0)" ::: "memory");
    BARRIER();

    unsigned t1[2][4], t2[2][4];         // top-2 per (rt,g)
    #pragma unroll
    for (int j = 0; j < 2; ++j)
        #pragma unroll
        for (int g = 0; g < 4; ++g) { t1[j][g] = 0xFFFFFFFFu; t2[j][g] = 0xFFFFFFFFu; }

    f32x4 acc[2];
    acc[0] = (f32x4){0.f, 0.f, 0.f, 0.f};
    acc[1] = (f32x4){0.f, 0.f, 0.f, 0.f};

    int p = 0;
    float pck = 0.f;
    #pragma unroll 1
    for (int t = 0; t < 32; ++t) {
        float ckv = ckl[t * 64 + cg * 16 + lid];

        // selection for tile t-1 (register-only, overlaps ds_read latency)
        if (t > 0) {
            unsigned tg = (unsigned)(t - 1);
            #pragma unroll
            for (int rt = 0; rt < 2; ++rt)
                #pragma unroll
                for (int g = 0; g < 4; ++g) {
                    float s = fmaf(-2.0f, acc[rt][g], pck);
                    unsigned key = (__float_as_uint(s) & 0xFFFFFFE0u) | tg;
                    unsigned o1 = t1[rt][g];
                    unsigned hi = key > o1 ? key : o1;
                    t1[rt][g] = key < o1 ? key : o1;
                    t2[rt][g] = hi < t2[rt][g] ? hi : t2[rt][g];
                    acc[rt][g] = 0.0f;
                }
        }
        pck = ckv;

        const short8v* Ev = reinterpret_cast<const short8v*>(lds + p * 32768);
        #pragma unroll
        for (int c = 0; c < 8; ++c) {
            short8v bf = Ev[c * 256 + kc * 64 + cg * 16 + lid];
            acc[0] = __builtin_amdgcn_mfma_f32_16x16x32_bf16(a[c][0], bf, acc[0], 0, 0, 0);
            acc[1] = __builtin_amdgcn_mfma_f32_16x16x32_bf16(a[c][1], bf, acc[1], 0, 0, 0);
        }

        BARRIER();                                   // all waves done with buf p
        if (t < 30) {
            stage(t + 2, p);                         // refill buf p (2-deep)
            asm volatile("s_waitcnt vmcnt(4)" ::: "memory");  // tile t+1 ready
        } else {
            asm volatile("s_waitcnt vmcnt(0)" ::: "memory");
        }
        BARRIER();
        p ^= 1;
    }
    // final selection (tile 31)
    {
        unsigned tg = 31u;
        #pragma unroll
        for (int rt = 0; rt < 2; ++rt)
            #pragma unroll
            for (int g = 0; g < 4; ++g) {
                float s = fmaf(-2.0f, acc[rt][g], pck);
                unsigned key = (__float_as_uint(s) & 0xFFFFFFE0u) | tg;
                unsigned o1 = t1[rt][g];
                unsigned hi = key > o1 ? key : o1;
                t1[rt][g] = key < o1 ? key : o1;
                t2[rt][g] = hi < t2[rt][g] ? hi : t2[rt][g];
            }
    }

    // ---- merge: 64 slots/row x 2 keys -> top-8 per row ----
    uint2* mb = reinterpret_cast<uint2*>(lds);            // [64 rows][64 slots] 32KB
    uint2* scr = reinterpret_cast<uint2*>(lds + 32768);   // [64][4][8] 16KB
    #pragma unroll
    for (int rt = 0; rt < 2; ++rt)
        #pragma unroll
        for (int g = 0; g < 4; ++g) {
            int row = rg * 32 + rt * 16 + kc * 4 + g;
            int slot = cg * 16 + lid;
            uint2 v; v.x = t1[rt][g]; v.y = t2[rt][g];
            mb[row * 64 + slot] = v;
        }
    BARRIER();
    if (tid < 256) {
        int row = tid >> 2, q = tid & 3;
        unsigned prev = 0; int prevj = -1;
        for (int i = 0; i < 8; ++i) {
            unsigned cur = 0xFFFFFFFFu; int curj = 0x7FFFFFFF;
            #pragma unroll
            for (int s = 0; s < 16; ++s) {
                int slot = q * 16 + ((s + tid) & 15);     // bank-spread rotation
                uint2 kv = mb[row * 64 + slot];
                int j0 = slot * 2;
                { unsigned k2=kv.x; int j=j0;   if ((k2>prev||(k2==prev&&j>prevj)) && (k2<cur||(k2==cur&&j<curj))) {cur=k2;curj=j;} }
                { unsigned k2=kv.y; int j=j0+1; if ((k2>prev||(k2==prev&&j>prevj)) && (k2<cur||(k2==cur&&j<curj))) {cur=k2;curj=j;} }
            }
            uint2 pr; pr.x = cur; pr.y = (unsigned)curj;
            scr[(row * 4 + q) * 8 + i] = pr;
            prev = cur; prevj = curj;
        }
    }
    BARRIER();
    if (tid < 64) {
        unsigned prev = 0; int prevj = -1;
        unsigned short codes[NCAND];
        for (int i = 0; i < NCAND; ++i) {
            unsigned cur = 0xFFFFFFFFu; int curj = 0x7FFFFFFF;
            for (int m = 0; m < 32; ++m) {
                int mm = (m + tid) & 31;
                uint2 pr = scr[tid * 32 + mm];
                unsigned k2 = pr.x; int j = (int)pr.y;
                if ((k2>prev||(k2==prev&&j>prevj)) && (k2<cur||(k2==cur&&j<curj))) {cur=k2;curj=j;}
            }
            prev = cur; prevj = curj;
            codes[i] = (unsigned short)((cur & 31u) * 64 + (curj >> 1));  // t*64+slot
        }
        ck[nb + tid] = *reinterpret_cast<uint4*>(codes);
    }
}

// ---- refine: np-fp32 rescore of 8 cands, writes ind + idx floats only ----
__global__ __launch_bounds__(256) void k_refine(const float* __restrict__ X,
                                                const float* __restrict__ E,
                                                const float* __restrict__ Cref,
                                                const uint4* __restrict__ ck,
                                                float* __restrict__ idx_out_f,
                                                int* __restrict__ ind) {
    __shared__ float Xl[RROWS][DD + 4];
    const int tid = threadIdx.x;
    const int n0 = blockIdx.x * RROWS;
    const int b = n0 >> 10;
    const int hw0 = n0 & 1023;
    const float* xbase = X + (size_t)b * CHW + hw0;
    #pragma unroll
    for (int it = 0; it < RROWS; ++it) {
        int idx = tid + it * 256;
        int d = idx >> 4, rr = idx & 15;
        Xl[rr][d] = xbase[(size_t)d * HW + rr];
    }
    __syncthreads();
    const int r = tid >> 4, c = tid & 15;
    const int sub = c & 7;
    uint4 ck4 = ck[n0 + r];
    const unsigned short* cs = reinterpret_cast<const unsigned short*>(&ck4);
    float A;
    {
#pragma clang fp contract(off)
        float r0[8], r1[8];
        #pragma unroll
        for (int j = 0; j < 8; ++j) { float t = Xl[r][j];       r0[j] = t * t; }
        #pragma unroll
        for (int j = 0; j < 8; ++j) { float t = Xl[r][128 + j]; r1[j] = t * t; }
        for (int i = 8; i < 128; i += 8) {
            #pragma unroll
            for (int j = 0; j < 8; ++j) { float t = Xl[r][i + j];       r0[j] += t * t; }
            #pragma unroll
            for (int j = 0; j < 8; ++j) { float t = Xl[r][128 + i + j]; r1[j] += t * t; }
        }
        float lo = ((r0[0]+r0[1])+(r0[2]+r0[3]))+((r0[4]+r0[5])+(r0[6]+r0[7]));
        float hi = ((r1[0]+r1[1])+(r1[2]+r1[3]))+((r1[4]+r1[5])+(r1[6]+r1[7]));
        A = lo + hi;
    }
    float bd = INFINITY; int bk = 0x7FFFFFFF;
    #pragma unroll 2
    for (int cc = 0; cc < 4; ++cc) {
        int k = cs[cc * 2 + (c >> 3)];
        const float* er = E + (size_t)k * DD;
        double p = 0.0;                          // f64: order-free proxy
        #pragma unroll
        for (int m = 0; m < 8; ++m) {
            float4 ev = *reinterpret_cast<const float4*>(er + sub * 32 + m * 4);
            float4 xv = *reinterpret_cast<const float4*>(&Xl[r][sub * 32 + m * 4]);
            p += (double)xv.x*ev.x + (double)xv.y*ev.y
               + (double)xv.z*ev.z + (double)xv.w*ev.w;
        }
        p += __shfl_xor(p, 1, 64);
        p += __shfl_xor(p, 2, 64);
        p += __shfl_xor(p, 4, 64);
        float dist;
        {
#pragma clang fp contract(off)
            float M  = (float)p;
            float Bt = 2.0f * M;
            float T1 = A - Bt;
            dist = T1 + Cref[k];
        }
        if (dist < bd || (dist == bd && k < bk)) { bd = dist; bk = k; }
    }
    {   // combine the two 8-lane candidate groups
        float bd2 = __shfl_xor(bd, 8, 64);
        int   bk2 = __shfl_xor(bk, 8, 64);
        if (bd2 < bd || (bd2 == bd && bk2 < bk)) { bd = bd2; bk = bk2; }
    }
    if (c == 0) {
        ind[n0 + r] = bk;
        idx_out_f[n0 + r] = (float)bk;
    }
}

// ---- out = x + BETA*(E[ind] - x), NCHW, fully-coalesced float4 (r5-proven) ----
__global__ __launch_bounds__(256) void k_out(const float* __restrict__ X,
                                             const float* __restrict__ E,
                                             const int* __restrict__ ind,
                                             float* __restrict__ out) {
    int gid = blockIdx.x * 256 + threadIdx.x;
    int e0 = gid << 2;
    int hw = e0 & 1023;
    int d  = (e0 >> 10) & 255;
    int b  = e0 >> 18;
    int n0 = (b << 10) | hw;

    float4 x = *reinterpret_cast<const float4*>(X + e0);
    int4  iv = *reinterpret_cast<const int4*>(ind + n0);
    float q0 = E[(size_t)iv.x * DD + d];
    float q1 = E[(size_t)iv.y * DD + d];
    float q2 = E[(size_t)iv.z * DD + d];
    float q3 = E[(size_t)iv.w * DD + d];
    float4 r;
    r.x = x.x + BETA * (q0 - x.x);
    r.y = x.y + BETA * (q1 - x.y);
    r.z = x.z + BETA * (q2 - x.z);
    r.w = x.w + BETA * (q3 - x.w);
    *reinterpret_cast<float4*>(out + e0) = r;
}

extern "C" void kernel_launch(void* const* d_in, const int* in_sizes, int n_in,
                              void* d_out, int out_size, void* d_ws, size_t ws_size,
                              hipStream_t stream) {
    const float* lat = (const float*)d_in[0];      // (32,256,32,32) fp32
    const float* emb = (const float*)d_in[1];      // (2048,256) fp32
    float* out   = (float*)d_out;                  // 8388608 floats (output 0)
    float* idx_f = out + (size_t)BB * DD * HW;     // 32768 floats (output 1)

    // EbfT scratch in d_out (read only by k_screen; k_out overwrites at end).
    // Ckey/Cref/ck/ind in d_ws (~656 KB, r3-proven budget).
    char*  ob   = (char*)d_out;
    uint4* EbfT = (uint4*)(ob);                    // 1 MB

    char* ws = (char*)d_ws;
    float* Ckey = (float*)(ws + 0);                // 8 KB
    float* Cref = (float*)(ws + 8192);             // 8 KB
    uint4* ck   = (uint4*)(ws + 16384);            // 512 KB (ushort8 per row)
    int*   ind  = (int*)(ws + 540672);             // 128 KB

    k_prep   <<<264, 256, 0, stream>>>(emb, EbfT, Cref, Ckey);
    k_screen <<<NN / 64, 512, 0, stream>>>(lat, EbfT, Ckey, ck);
    k_refine <<<NN / RROWS, 256, 0, stream>>>(lat, emb, Cref, ck, idx_f, ind);
    k_out    <<<(BB * DD * HW) / 4 / 256, 256, 0, stream>>>(lat, emb, ind, out);
}

// Round 13
// 152.308 us; speedup vs baseline: 1.2882x; 1.2882x over previous
//
#include <hip/hip_runtime.h>
#include <math.h>

#define BB 32
#define DD 256
#define KK 2048
#define HW 1024
#define CHW (DD*HW)
#define NN (BB*HW)         // 32768 rows
#define BETA 0.25f
#define RROWS 32
#define NCAND 8
#define BIAS 0.125f

typedef __attribute__((ext_vector_type(8))) short short8v;   // 8 bf16 (4 VGPR)
typedef __attribute__((ext_vector_type(4))) float f32x4;

typedef const __attribute__((address_space(1))) void gv_t;
typedef __attribute__((address_space(3))) void lv_t;

__device__ __forceinline__ void gl_lds16(const void* g, void* l) {
    // LDS dest = wave-uniform base (+ lane*16 by HW); global src = per-lane addr
    __builtin_amdgcn_global_load_lds((gv_t*)g, (lv_t*)l, 16, 0, 0);
}

__device__ __forceinline__ unsigned bfr(float f) {           // fp32 -> bf16 RNE
    unsigned u = __float_as_uint(f);
    return (u + 0x7FFFu + ((u >> 16) & 1u)) >> 16;
}
__device__ __forceinline__ unsigned bfpack(float lo, float hi) {
    return bfr(lo) | (bfr(hi) << 16);
}

#define BARRIER() do { asm volatile("" ::: "memory"); \
                       __builtin_amdgcn_s_barrier();  \
                       asm volatile("" ::: "memory"); } while (0)

// ---- prep: blocks 0..255 convert E->bf16 tiled (unchanged);
//      blocks 256..767: ONE WAVE PER CODE computes np-pairwise C bitwise.
//      Chain j of half h: r[j] = sum_{i=0..15} e[h*128+8i+j]^2, fp32 seq adds
//      (init 0 is exact), then the fixed pairwise combine tree on lane 0. ----
__global__ __launch_bounds__(256) void k_prep(const float* __restrict__ E,
                                              uint4* __restrict__ EbfT,
                                              float* __restrict__ Cref,
                                              float* __restrict__ Ckey) {
    int bid = blockIdx.x;
    if (bid < 256) {
        int u = bid * 256 + threadIdx.x;                 // 0..65535
        int code = u & 63, kc = (u >> 6) & 3, c = (u >> 8) & 7, t = u >> 11;
        int k = t * 64 + code;
        const float* s = E + ((size_t)k * DD + c * 32 + kc * 8);
        float4 f0 = *reinterpret_cast<const float4*>(s);
        float4 f1 = *reinterpret_cast<const float4*>(s + 4);
        uint4 o;
        o.x = bfpack(f0.x, f0.y); o.y = bfpack(f0.z, f0.w);
        o.z = bfpack(f1.x, f1.y); o.w = bfpack(f1.z, f1.w);
        EbfT[u] = o;
    } else {
        const int w = threadIdx.x >> 6;                  // 4 waves/block
        const int lane = threadIdx.x & 63;
        const int k = (bid - 256) * 4 + w;               // one code per wave
        float racc = 0.0f;
        if (lane < 16) {
#pragma clang fp contract(off)
            const int j = lane & 7, h = lane >> 3;
            const float* e = E + (size_t)k * DD + h * 128 + j;
            for (int i = 0; i < 16; ++i) {
                float t = e[i * 8];
                racc += t * t;                           // mul then add, seq
            }
        }
        float v0 = __shfl(racc, 0, 64),  v1 = __shfl(racc, 1, 64);
        float v2 = __shfl(racc, 2, 64),  v3 = __shfl(racc, 3, 64);
        float v4 = __shfl(racc, 4, 64),  v5 = __shfl(racc, 5, 64);
        float v6 = __shfl(racc, 6, 64),  v7 = __shfl(racc, 7, 64);
        float v8 = __shfl(racc, 8, 64),  v9 = __shfl(racc, 9, 64);
        float va = __shfl(racc, 10, 64), vb = __shfl(racc, 11, 64);
        float vc = __shfl(racc, 12, 64), vd = __shfl(racc, 13, 64);
        float ve = __shfl(racc, 14, 64), vf = __shfl(racc, 15, 64);
        if (lane == 0) {
#pragma clang fp contract(off)
            float lo = ((v0 + v1) + (v2 + v3)) + ((v4 + v5) + (v6 + v7));
            float hi = ((v8 + v9) + (va + vb)) + ((vc + vd) + (ve + vf));
            float res = lo + hi;
            Cref[k] = res;
            Ckey[k] = res + BIAS;
        }
    }
}

// ---- MFMA screen (r11-exact): 512 thr = 8 waves (4 row-grp x 16 rows,
//      2 code-grp), 64 rows/block, K-split x2 (16 tiles/block), grid 1024.
//      A = 32 VGPR in regs; E LDS dbuf + counted vmcnt(4). PROVEN 83 us. ----
__global__ __launch_bounds__(512, 4) void k_screen(
        const float* __restrict__ X, const uint4* __restrict__ EbfT,
        const float* __restrict__ Ckey, uint2* __restrict__ ck)
{
    __shared__ __align__(1024) char lds[69632];   // 2x32KB E dbuf | 4KB ckl

    const int tid = threadIdx.x;
    const int w = tid >> 6;              // 0..7
    const int rg = w >> 1;               // 0..3 row group (16 rows each)
    const int cg = w & 1;                // 0..1 code group (32 codes each)
    const int lane = tid & 63;
    const int lid = lane & 15, kc = lane >> 4;
    const int bid = blockIdx.x;
    const int half = bid & 1;
    const int tbase = half * 16;
    const int nb = (bid >> 1) * 64;
    const int b = nb >> 10;              // 64 | 1024 -> single b per block
    const int hw0 = nb & 1023;

    float* ckl = (float*)(lds + 65536);

    float ckg0 = Ckey[tbase * 64 + tid];
    float ckg1 = Ckey[tbase * 64 + 512 + tid];

    short8v a[8];                        // 16 rows x 256 d: 32 VGPR
    {
        const float* xb = X + (size_t)b * CHW + (hw0 + rg * 16 + lid);
        #pragma unroll
        for (int c = 0; c < 8; ++c) {
            const float* pp = xb + (size_t)(c * 32 + kc * 8) * HW;
            float f[8];
            #pragma unroll
            for (int j = 0; j < 8; ++j) f[j] = pp[(size_t)j * HW];
            uint4 v;
            v.x = bfpack(f[0], f[1]); v.y = bfpack(f[2], f[3]);
            v.z = bfpack(f[4], f[5]); v.w = bfpack(f[6], f[7]);
            a[c] = *reinterpret_cast<short8v*>(&v);
        }
    }
    ckl[tid] = ckg0;
    ckl[tid + 512] = ckg1;

    auto stage = [&](int t, int p) {     // t local (0..15); 8 waves x 4 x 1KB
        const uint4* src = EbfT + ((size_t)(tbase + t) * 2048 + w * 256 + lane);
        char* dst = lds + p * 32768 + (w * 256) * 16;
        #pragma unroll
        for (int i = 0; i < 4; ++i)
            gl_lds16(src + i * 64, dst + i * 1024);
    };
    stage(0, 0);
    stage(1, 1);
    asm volatile("s_waitcnt vmcnt(0) lgkmcnt(0)" ::: "memory");
    BARRIER();

    unsigned t1[2][4], t2[2][4];         // top-2 per (ct,g)
    #pragma unroll
    for (int j = 0; j < 2; ++j)
        #pragma unroll
        for (int g = 0; g < 4; ++g) { t1[j][g] = 0xFFFFFFFFu; t2[j][g] = 0xFFFFFFFFu; }

    f32x4 acc[2];
    acc[0] = (f32x4){0.f, 0.f, 0.f, 0.f};
    acc[1] = (f32x4){0.f, 0.f, 0.f, 0.f};

    int p = 0;
    float pck0 = 0.f, pck1 = 0.f;
    #pragma unroll 1
    for (int tt = 0; tt < 16; ++tt) {
        float ck0 = ckl[tt * 64 + cg * 32 + lid];
        float ck1 = ckl[tt * 64 + cg * 32 + 16 + lid];

        if (tt > 0) {
            unsigned tg = (unsigned)(tbase + tt - 1);
            #pragma unroll
            for (int ct = 0; ct < 2; ++ct) {
                float cv = ct ? pck1 : pck0;
                #pragma unroll
                for (int g = 0; g < 4; ++g) {
                    float s = fmaf(-2.0f, acc[ct][g], cv);
                    unsigned key = (__float_as_uint(s) & 0xFFFFFFE0u) | tg;
                    unsigned o1 = t1[ct][g];
                    unsigned hi = key > o1 ? key : o1;
                    t1[ct][g] = key < o1 ? key : o1;
                    t2[ct][g] = hi < t2[ct][g] ? hi : t2[ct][g];
                    acc[ct][g] = 0.0f;
                }
            }
        }
        pck0 = ck0; pck1 = ck1;

        const short8v* Ev = reinterpret_cast<const short8v*>(lds + p * 32768);
        #pragma unroll
        for (int c = 0; c < 8; ++c) {
            short8v b0 = Ev[c * 256 + kc * 64 + cg * 32 + lid];
            short8v b1 = Ev[c * 256 + kc * 64 + cg * 32 + 16 + lid];
            acc[0] = __builtin_amdgcn_mfma_f32_16x16x32_bf16(a[c], b0, acc[0], 0, 0, 0);
            acc[1] = __builtin_amdgcn_mfma_f32_16x16x32_bf16(a[c], b1, acc[1], 0, 0, 0);
        }

        BARRIER();
        if (tt < 14) {
            stage(tt + 2, p);
            asm volatile("s_waitcnt vmcnt(4)" ::: "memory");
        } else {
            asm volatile("s_waitcnt vmcnt(0)" ::: "memory");
        }
        BARRIER();
        p ^= 1;
    }
    {
        unsigned tg = (unsigned)(tbase + 15);
        #pragma unroll
        for (int ct = 0; ct < 2; ++ct) {
            float cv = ct ? pck1 : pck0;
            #pragma unroll
            for (int g = 0; g < 4; ++g) {
                float s = fmaf(-2.0f, acc[ct][g], cv);
                unsigned key = (__float_as_uint(s) & 0xFFFFFFE0u) | tg;
                unsigned o1 = t1[ct][g];
                unsigned hi = key > o1 ? key : o1;
                t1[ct][g] = key < o1 ? key : o1;
                t2[ct][g] = hi < t2[ct][g] ? hi : t2[ct][g];
            }
        }
    }

    // ---- merge: 64 slots/row x 2 keys -> top-4 of this half ----
    uint2* mb = reinterpret_cast<uint2*>(lds);            // [64 rows][64 slots] 32KB
    uint2* scr = reinterpret_cast<uint2*>(lds + 32768);   // [64][4][4] 8KB
    #pragma unroll
    for (int ct = 0; ct < 2; ++ct)
        #pragma unroll
        for (int g = 0; g < 4; ++g) {
            int row = rg * 16 + kc * 4 + g;
            int slot = cg * 32 + ct * 16 + lid;
            uint2 v; v.x = t1[ct][g]; v.y = t2[ct][g];
            mb[row * 64 + slot] = v;
        }
    BARRIER();
    if (tid < 256) {
        int row = tid >> 2, q = tid & 3;
        unsigned prev = 0; int prevj = -1;
        for (int i = 0; i < 4; ++i) {
            unsigned cur = 0xFFFFFFFFu; int curj = 0x7FFFFFFF;
            #pragma unroll
            for (int s = 0; s < 16; ++s) {
                int slot = q * 16 + ((s + tid) & 15);     // bank-spread rotation
                uint2 kv = mb[row * 64 + slot];
                int j0 = slot * 2;
                { unsigned k2=kv.x; int j=j0;   if ((k2>prev||(k2==prev&&j>prevj)) && (k2<cur||(k2==cur&&j<curj))) {cur=k2;curj=j;} }
                { unsigned k2=kv.y; int j=j0+1; if ((k2>prev||(k2==prev&&j>prevj)) && (k2<cur||(k2==cur&&j<curj))) {cur=k2;curj=j;} }
            }
            uint2 pr; pr.x = cur; pr.y = (unsigned)curj;
            scr[(row * 4 + q) * 4 + i] = pr;
            prev = cur; prevj = curj;
        }
    }
    BARRIER();
    if (tid < 64) {
        unsigned prev = 0; int prevj = -1;
        unsigned short codes[4];
        for (int i = 0; i < 4; ++i) {
            unsigned cur = 0xFFFFFFFFu; int curj = 0x7FFFFFFF;
            for (int m = 0; m < 16; ++m) {
                int mm = (m + tid) & 15;
                uint2 pr = scr[tid * 16 + mm];
                unsigned k2 = pr.x; int j = (int)pr.y;
                if ((k2>prev||(k2==prev&&j>prevj)) && (k2<cur||(k2==cur&&j<curj))) {cur=k2;curj=j;}
            }
            prev = cur; prevj = curj;
            codes[i] = (unsigned short)((cur & 31u) * 64 + (curj >> 1));  // t*64+slot
        }
        uint2 o;
        o.x = (unsigned)codes[0] | ((unsigned)codes[1] << 16);
        o.y = (unsigned)codes[2] | ((unsigned)codes[3] << 16);
        ck[(size_t)(nb + tid) * 2 + half] = o;
    }
}

// ---- refine+out v4: 512 thr, 32 rows/block, 16 lanes/row. np-fp32 rescore
//      (split-dot f64 proxy), then fully-coalesced fused output write. ----
__global__ __launch_bounds__(512) void k_refineout(const float* __restrict__ X,
                                                   const float* __restrict__ E,
                                                   const float* __restrict__ Cref,
                                                   const uint2* __restrict__ ck,
                                                   float* __restrict__ idx_out_f,
                                                   float* __restrict__ out) {
    __shared__ float Xl[RROWS][DD + 4];
    __shared__ float El[RROWS][DD + 4];
    __shared__ int bk_l[RROWS];
    const int tid = threadIdx.x;
    const int n0 = blockIdx.x * RROWS;
    const int b = n0 >> 10;
    const int hw0 = n0 & 1023;
    const float* xbase = X + (size_t)b * CHW + hw0;
    #pragma unroll
    for (int it = 0; it < 16; ++it) {
        int idx = tid + it * 512;                 // 0..8191
        int d = idx >> 5, rr = idx & 31;          // 128B coalesced runs
        Xl[rr][d] = xbase[(size_t)d * HW + rr];
    }
    __syncthreads();
    const int r = tid >> 4, c = tid & 15;
    const int sub = c & 7;
    uint4 ck4 = reinterpret_cast<const uint4*>(ck)[n0 + r];   // 8 ushort codes
    const unsigned short* cs = reinterpret_cast<const unsigned short*>(&ck4);
    float A;
    {
#pragma clang fp contract(off)
        float r0[8], r1[8];
        #pragma unroll
        for (int j = 0; j < 8; ++j) { float t = Xl[r][j];       r0[j] = t * t; }
        #pragma unroll
        for (int j = 0; j < 8; ++j) { float t = Xl[r][128 + j]; r1[j] = t * t; }
        for (int i = 8; i < 128; i += 8) {
            #pragma unroll
            for (int j = 0; j < 8; ++j) { float t = Xl[r][i + j];       r0[j] += t * t; }
            #pragma unroll
            for (int j = 0; j < 8; ++j) { float t = Xl[r][128 + i + j]; r1[j] += t * t; }
        }
        float lo = ((r0[0]+r0[1])+(r0[2]+r0[3]))+((r0[4]+r0[5])+(r0[6]+r0[7]));
        float hi = ((r1[0]+r1[1])+(r1[2]+r1[3]))+((r1[4]+r1[5])+(r1[6]+r1[7]));
        A = lo + hi;
    }
    float bd = INFINITY; int bk = 0x7FFFFFFF;
    #pragma unroll 2
    for (int cc = 0; cc < 4; ++cc) {
        int k = cs[cc * 2 + (c >> 3)];
        const float* er = E + (size_t)k * DD;
        double p = 0.0;                          // f64: order-free proxy
        #pragma unroll
        for (int m = 0; m < 8; ++m) {
            float4 ev = *reinterpret_cast<const float4*>(er + sub * 32 + m * 4);
            float4 xv = *reinterpret_cast<const float4*>(&Xl[r][sub * 32 + m * 4]);
            p += (double)xv.x*ev.x + (double)xv.y*ev.y
               + (double)xv.z*ev.z + (double)xv.w*ev.w;
        }
        p += __shfl_xor(p, 1, 64);
        p += __shfl_xor(p, 2, 64);
        p += __shfl_xor(p, 4, 64);
        float dist;
        {
#pragma clang fp contract(off)
            float M  = (float)p;
            float Bt = 2.0f * M;
            float T1 = A - Bt;
            dist = T1 + Cref[k];
        }
        if (dist < bd || (dist == bd && k < bk)) { bd = dist; bk = k; }
    }
    {   // combine the two 8-lane candidate groups
        float bd2 = __shfl_xor(bd, 8, 64);
        int   bk2 = __shfl_xor(bk, 8, 64);
        if (bd2 < bd || (bd2 == bd && bk2 < bk)) { bd = bd2; bk = bk2; }
    }
    if (c == 0) {
        bk_l[r] = bk;
        idx_out_f[n0 + r] = (float)bk;
    }
    __syncthreads();
    {   // stage winning E rows coalesced (256B runs per row)
        int kk = bk_l[r];
        const float* er = E + (size_t)kk * DD;
        #pragma unroll
        for (int m = 0; m < 4; ++m)
            *reinterpret_cast<float4*>(&El[r][m * 64 + c * 4]) =
                *reinterpret_cast<const float4*>(er + m * 64 + c * 4);
    }
    __syncthreads();
    {   // fused output: out[b][d][hw0+rr], rr-fastest -> 2x128B segs per store
        const int rr = tid & 31;
        const int d0 = tid >> 5;                 // 0..15
        float* ob = out + (size_t)b * CHW + hw0 + rr;
        #pragma unroll
        for (int it = 0; it < 16; ++it) {
            int d = d0 + it * 16;
            float x = Xl[rr][d];
            float qv = El[rr][d];
            ob[(size_t)d * HW] = x + BETA * (qv - x);
        }
    }
}

extern "C" void kernel_launch(void* const* d_in, const int* in_sizes, int n_in,
                              void* d_out, int out_size, void* d_ws, size_t ws_size,
                              hipStream_t stream) {
    const float* lat = (const float*)d_in[0];      // (32,256,32,32) fp32
    const float* emb = (const float*)d_in[1];      // (2048,256) fp32
    float* out   = (float*)d_out;                  // 8388608 floats (output 0)
    float* idx_f = out + (size_t)BB * DD * HW;     // 32768 floats (output 1)

    // EbfT scratch in d_out (read only by k_screen, which completes before
    // k_refineout writes out). Ckey/Cref/ck in d_ws (~530 KB).
    char*  ob   = (char*)d_out;
    uint4* EbfT = (uint4*)(ob);                    // 1 MB

    char* ws = (char*)d_ws;
    float* Ckey = (float*)(ws + 0);                // 8 KB
    float* Cref = (float*)(ws + 8192);             // 8 KB
    uint2* ck   = (uint2*)(ws + 16384);            // 512 KB (2 x ushort4 per row)

    k_prep      <<<768, 256, 0, stream>>>(emb, EbfT, Cref, Ckey);
    k_screen    <<<NN / 64 * 2, 512, 0, stream>>>(lat, EbfT, Ckey, ck);
    k_refineout <<<NN / RROWS, 512, 0, stream>>>(lat, emb, Cref, ck, idx_f, out);
}

// Round 15
// 150.093 us; speedup vs baseline: 1.3072x; 1.0148x over previous
//
#include <hip/hip_runtime.h>
#include <math.h>

#define BB 32
#define DD 256
#define KK 2048
#define HW 1024
#define CHW (DD*HW)
#define NN (BB*HW)         // 32768 rows
#define BETA 0.25f
#define RROWS 32
#define NCAND 8
#define BIAS 0.125f

typedef __attribute__((ext_vector_type(8))) short short8v;   // 8 bf16 (4 VGPR)
typedef __attribute__((ext_vector_type(4))) float f32x4;

typedef const __attribute__((address_space(1))) void gv_t;
typedef __attribute__((address_space(3))) void lv_t;

__device__ __forceinline__ void gl_lds16(const void* g, void* l) {
    // LDS dest = wave-uniform base (+ lane*16 by HW); global src = per-lane addr
    __builtin_amdgcn_global_load_lds((gv_t*)g, (lv_t*)l, 16, 0, 0);
}

__device__ __forceinline__ unsigned bfr(float f) {           // fp32 -> bf16 RNE
    unsigned u = __float_as_uint(f);
    return (u + 0x7FFFu + ((u >> 16) & 1u)) >> 16;
}
__device__ __forceinline__ unsigned bfpack(float lo, float hi) {
    return bfr(lo) | (bfr(hi) << 16);
}

#define BARRIER() do { asm volatile("" ::: "memory"); \
                       __builtin_amdgcn_s_barrier();  \
                       asm volatile("" ::: "memory"); } while (0)

// ---- prep: blocks 0..255 convert E->bf16 tiled; blocks 256..767: one wave
//      per code computes np-pairwise C bitwise (r13-proven). ----
__global__ __launch_bounds__(256) void k_prep(const float* __restrict__ E,
                                              uint4* __restrict__ EbfT,
                                              float* __restrict__ Cref,
                                              float* __restrict__ Ckey) {
    int bid = blockIdx.x;
    if (bid < 256) {
        int u = bid * 256 + threadIdx.x;                 // 0..65535
        int code = u & 63, kc = (u >> 6) & 3, c = (u >> 8) & 7, t = u >> 11;
        int k = t * 64 + code;
        const float* s = E + ((size_t)k * DD + c * 32 + kc * 8);
        float4 f0 = *reinterpret_cast<const float4*>(s);
        float4 f1 = *reinterpret_cast<const float4*>(s + 4);
        uint4 o;
        o.x = bfpack(f0.x, f0.y); o.y = bfpack(f0.z, f0.w);
        o.z = bfpack(f1.x, f1.y); o.w = bfpack(f1.z, f1.w);
        EbfT[u] = o;
    } else {
        const int w = threadIdx.x >> 6;                  // 4 waves/block
        const int lane = threadIdx.x & 63;
        const int k = (bid - 256) * 4 + w;               // one code per wave
        float racc = 0.0f;
        if (lane < 16) {
#pragma clang fp contract(off)
            const int j = lane & 7, h = lane >> 3;
            const float* e = E + (size_t)k * DD + h * 128 + j;
            for (int i = 0; i < 16; ++i) {
                float t = e[i * 8];
                racc += t * t;                           // mul then add, seq
            }
        }
        float v0 = __shfl(racc, 0, 64),  v1 = __shfl(racc, 1, 64);
        float v2 = __shfl(racc, 2, 64),  v3 = __shfl(racc, 3, 64);
        float v4 = __shfl(racc, 4, 64),  v5 = __shfl(racc, 5, 64);
        float v6 = __shfl(racc, 6, 64),  v7 = __shfl(racc, 7, 64);
        float v8 = __shfl(racc, 8, 64),  v9 = __shfl(racc, 9, 64);
        float va = __shfl(racc, 10, 64), vb = __shfl(racc, 11, 64);
        float vc = __shfl(racc, 12, 64), vd = __shfl(racc, 13, 64);
        float ve = __shfl(racc, 14, 64), vf = __shfl(racc, 15, 64);
        if (lane == 0) {
#pragma clang fp contract(off)
            float lo = ((v0 + v1) + (v2 + v3)) + ((v4 + v5) + (v6 + v7));
            float hi = ((v8 + v9) + (va + vb)) + ((vc + vd) + (ve + vf));
            float res = lo + hi;
            Cref[k] = res;
            Ckey[k] = res + BIAS;
        }
    }
}

// ---- MFMA screen (r11-exact, FROZEN): 512 thr = 8 waves (4 row-grp x 16 rows,
//      2 code-grp), 64 rows/block, K-split x2 (16 tiles/block), grid 1024.
//      A = 32 VGPR in regs; E LDS dbuf + counted vmcnt(4). PROVEN 82 us. ----
__global__ __launch_bounds__(512, 4) void k_screen(
        const float* __restrict__ X, const uint4* __restrict__ EbfT,
        const float* __restrict__ Ckey, uint2* __restrict__ ck)
{
    __shared__ __align__(1024) char lds[69632];   // 2x32KB E dbuf | 4KB ckl

    const int tid = threadIdx.x;
    const int w = tid >> 6;              // 0..7
    const int rg = w >> 1;               // 0..3 row group (16 rows each)
    const int cg = w & 1;                // 0..1 code group (32 codes each)
    const int lane = tid & 63;
    const int lid = lane & 15, kc = lane >> 4;
    const int bid = blockIdx.x;
    const int half = bid & 1;
    const int tbase = half * 16;
    const int nb = (bid >> 1) * 64;
    const int b = nb >> 10;              // 64 | 1024 -> single b per block
    const int hw0 = nb & 1023;

    float* ckl = (float*)(lds + 65536);

    float ckg0 = Ckey[tbase * 64 + tid];
    float ckg1 = Ckey[tbase * 64 + 512 + tid];

    short8v a[8];                        // 16 rows x 256 d: 32 VGPR
    {
        const float* xb = X + (size_t)b * CHW + (hw0 + rg * 16 + lid);
        #pragma unroll
        for (int c = 0; c < 8; ++c) {
            const float* pp = xb + (size_t)(c * 32 + kc * 8) * HW;
            float f[8];
            #pragma unroll
            for (int j = 0; j < 8; ++j) f[j] = pp[(size_t)j * HW];
            uint4 v;
            v.x = bfpack(f[0], f[1]); v.y = bfpack(f[2], f[3]);
            v.z = bfpack(f[4], f[5]); v.w = bfpack(f[6], f[7]);
            a[c] = *reinterpret_cast<short8v*>(&v);
        }
    }
    ckl[tid] = ckg0;
    ckl[tid + 512] = ckg1;

    auto stage = [&](int t, int p) {     // t local (0..15); 8 waves x 4 x 1KB
        const uint4* src = EbfT + ((size_t)(tbase + t) * 2048 + w * 256 + lane);
        char* dst = lds + p * 32768 + (w * 256) * 16;
        #pragma unroll
        for (int i = 0; i < 4; ++i)
            gl_lds16(src + i * 64, dst + i * 1024);
    };
    stage(0, 0);
    stage(1, 1);
    asm volatile("s_waitcnt vmcnt(0) lgkmcnt(0)" ::: "memory");
    BARRIER();

    unsigned t1[2][4], t2[2][4];         // top-2 per (ct,g)
    #pragma unroll
    for (int j = 0; j < 2; ++j)
        #pragma unroll
        for (int g = 0; g < 4; ++g) { t1[j][g] = 0xFFFFFFFFu; t2[j][g] = 0xFFFFFFFFu; }

    f32x4 acc[2];
    acc[0] = (f32x4){0.f, 0.f, 0.f, 0.f};
    acc[1] = (f32x4){0.f, 0.f, 0.f, 0.f};

    int p = 0;
    float pck0 = 0.f, pck1 = 0.f;
    #pragma unroll 1
    for (int tt = 0; tt < 16; ++tt) {
        float ck0 = ckl[tt * 64 + cg * 32 + lid];
        float ck1 = ckl[tt * 64 + cg * 32 + 16 + lid];

        if (tt > 0) {
            unsigned tg = (unsigned)(tbase + tt - 1);
            #pragma unroll
            for (int ct = 0; ct < 2; ++ct) {
                float cv = ct ? pck1 : pck0;
                #pragma unroll
                for (int g = 0; g < 4; ++g) {
                    float s = fmaf(-2.0f, acc[ct][g], cv);
                    unsigned key = (__float_as_uint(s) & 0xFFFFFFE0u) | tg;
                    unsigned o1 = t1[ct][g];
                    unsigned hi = key > o1 ? key : o1;
                    t1[ct][g] = key < o1 ? key : o1;
                    t2[ct][g] = hi < t2[ct][g] ? hi : t2[ct][g];
                    acc[ct][g] = 0.0f;
                }
            }
        }
        pck0 = ck0; pck1 = ck1;

        const short8v* Ev = reinterpret_cast<const short8v*>(lds + p * 32768);
        #pragma unroll
        for (int c = 0; c < 8; ++c) {
            short8v b0 = Ev[c * 256 + kc * 64 + cg * 32 + lid];
            short8v b1 = Ev[c * 256 + kc * 64 + cg * 32 + 16 + lid];
            acc[0] = __builtin_amdgcn_mfma_f32_16x16x32_bf16(a[c], b0, acc[0], 0, 0, 0);
            acc[1] = __builtin_amdgcn_mfma_f32_16x16x32_bf16(a[c], b1, acc[1], 0, 0, 0);
        }

        BARRIER();
        if (tt < 14) {
            stage(tt + 2, p);
            asm volatile("s_waitcnt vmcnt(4)" ::: "memory");
        } else {
            asm volatile("s_waitcnt vmcnt(0)" ::: "memory");
        }
        BARRIER();
        p ^= 1;
    }
    {
        unsigned tg = (unsigned)(tbase + 15);
        #pragma unroll
        for (int ct = 0; ct < 2; ++ct) {
            float cv = ct ? pck1 : pck0;
            #pragma unroll
            for (int g = 0; g < 4; ++g) {
                float s = fmaf(-2.0f, acc[ct][g], cv);
                unsigned key = (__float_as_uint(s) & 0xFFFFFFE0u) | tg;
                unsigned o1 = t1[ct][g];
                unsigned hi = key > o1 ? key : o1;
                t1[ct][g] = key < o1 ? key : o1;
                t2[ct][g] = hi < t2[ct][g] ? hi : t2[ct][g];
            }
        }
    }

    // ---- merge: 64 slots/row x 2 keys -> top-4 of this half ----
    uint2* mb = reinterpret_cast<uint2*>(lds);            // [64 rows][64 slots] 32KB
    uint2* scr = reinterpret_cast<uint2*>(lds + 32768);   // [64][4][4] 8KB
    #pragma unroll
    for (int ct = 0; ct < 2; ++ct)
        #pragma unroll
        for (int g = 0; g < 4; ++g) {
            int row = rg * 16 + kc * 4 + g;
            int slot = cg * 32 + ct * 16 + lid;
            uint2 v; v.x = t1[ct][g]; v.y = t2[ct][g];
            mb[row * 64 + slot] = v;
        }
    BARRIER();
    if (tid < 256) {
        int row = tid >> 2, q = tid & 3;
        unsigned prev = 0; int prevj = -1;
        for (int i = 0; i < 4; ++i) {
            unsigned cur = 0xFFFFFFFFu; int curj = 0x7FFFFFFF;
            #pragma unroll
            for (int s = 0; s < 16; ++s) {
                int slot = q * 16 + ((s + tid) & 15);     // bank-spread rotation
                uint2 kv = mb[row * 64 + slot];
                int j0 = slot * 2;
                { unsigned k2=kv.x; int j=j0;   if ((k2>prev||(k2==prev&&j>prevj)) && (k2<cur||(k2==cur&&j<curj))) {cur=k2;curj=j;} }
                { unsigned k2=kv.y; int j=j0+1; if ((k2>prev||(k2==prev&&j>prevj)) && (k2<cur||(k2==cur&&j<curj))) {cur=k2;curj=j;} }
            }
            uint2 pr; pr.x = cur; pr.y = (unsigned)curj;
            scr[(row * 4 + q) * 4 + i] = pr;
            prev = cur; prevj = curj;
        }
    }
    BARRIER();
    if (tid < 64) {
        unsigned prev = 0; int prevj = -1;
        unsigned short codes[4];
        for (int i = 0; i < 4; ++i) {
            unsigned cur = 0xFFFFFFFFu; int curj = 0x7FFFFFFF;
            for (int m = 0; m < 16; ++m) {
                int mm = (m + tid) & 15;
                uint2 pr = scr[tid * 16 + mm];
                unsigned k2 = pr.x; int j = (int)pr.y;
                if ((k2>prev||(k2==prev&&j>prevj)) && (k2<cur||(k2==cur&&j<curj))) {cur=k2;curj=j;}
            }
            prev = cur; prevj = curj;
            codes[i] = (unsigned short)((cur & 31u) * 64 + (curj >> 1));  // t*64+slot
        }
        uint2 o;
        o.x = (unsigned)codes[0] | ((unsigned)codes[1] << 16);
        o.y = (unsigned)codes[2] | ((unsigned)codes[3] << 16);
        ck[(size_t)(nb + tid) * 2 + half] = o;
    }
}

// ---- refine+out v5: 512 thr, 32 rows/block, 16 lanes/row. A computed
//      WAVE-PARALLEL (16 lanes, 1 np-chain each + bitwise shfl tree). ----
__global__ __launch_bounds__(512) void k_refineout(const float* __restrict__ X,
                                                   const float* __restrict__ E,
                                                   const float* __restrict__ Cref,
                                                   const uint2* __restrict__ ck,
                                                   float* __restrict__ idx_out_f,
                                                   float* __restrict__ out) {
    __shared__ float Xl[RROWS][DD + 4];
    __shared__ float El[RROWS][DD + 4];
    __shared__ int bk_l[RROWS];
    const int tid = threadIdx.x;
    const int n0 = blockIdx.x * RROWS;
    const int b = n0 >> 10;
    const int hw0 = n0 & 1023;
    const float* xbase = X + (size_t)b * CHW + hw0;
    #pragma unroll
    for (int it = 0; it < 16; ++it) {
        int idx = tid + it * 512;                 // 0..8191
        int d = idx >> 5, rr = idx & 31;          // 128B coalesced runs
        Xl[rr][d] = xbase[(size_t)d * HW + rr];
    }
    __syncthreads();
    const int r = tid >> 4, c = tid & 15;
    const int sub = c & 7;
    uint4 ck4 = reinterpret_cast<const uint4*>(ck)[n0 + r];   // 8 ushort codes
    const unsigned short* cs = reinterpret_cast<const unsigned short*>(&ck4);

    // ---- A = np-pairwise sum(x^2), wave-parallel bitwise emulation:
    //      lane c owns chain (j=c&7, h=c>>3): racc = sum_i Xl[r][h*128+8i+j]^2
    //      (sequential fp32 mul+add, init 0 exact). Combine: xor-1,2,4 within
    //      8 reproduces ((r0+r1)+(r2+r3))+((r4+r5)+(r6+r7)) (IEEE add is
    //      commutative -> lane-order swaps bit-identical); xor-8 gives lo+hi.
    float A;
    {
        float racc;
        {
#pragma clang fp contract(off)
            const int j = c & 7, h = c >> 3;
            const float* xr = &Xl[r][h * 128 + j];
            racc = 0.0f;
            for (int i = 0; i < 16; ++i) {
                float t = xr[i * 8];
                racc += t * t;
            }
        }
        float w1 = __shfl_xor(racc, 1, 16);
        float s1, s2, s4;
        {
#pragma clang fp contract(off)
            s1 = racc + w1;
        }
        float w2 = __shfl_xor(s1, 2, 16);
        {
#pragma clang fp contract(off)
            s2 = s1 + w2;
        }
        float w4 = __shfl_xor(s2, 4, 16);
        {
#pragma clang fp contract(off)
            s4 = s2 + w4;                         // lo (h=0 lanes) / hi (h=1)
        }
        float w8 = __shfl_xor(s4, 8, 16);
        {
#pragma clang fp contract(off)
            A = s4 + w8;                          // lo + hi
        }
    }

    float bd = INFINITY; int bk = 0x7FFFFFFF;
    #pragma unroll 2
    for (int cc = 0; cc < 4; ++cc) {
        int k = cs[cc * 2 + (c >> 3)];
        const float* er = E + (size_t)k * DD;
        double p = 0.0;                          // f64: order-free proxy
        #pragma unroll
        for (int m = 0; m < 8; ++m) {
            float4 ev = *reinterpret_cast<const float4*>(er + sub * 32 + m * 4);
            float4 xv = *reinterpret_cast<const float4*>(&Xl[r][sub * 32 + m * 4]);
            p += (double)xv.x*ev.x + (double)xv.y*ev.y
               + (double)xv.z*ev.z + (double)xv.w*ev.w;
        }
        p += __shfl_xor(p, 1, 64);
        p += __shfl_xor(p, 2, 64);
        p += __shfl_xor(p, 4, 64);
        float dist;
        {
#pragma clang fp contract(off)
            float M  = (float)p;
            float Bt = 2.0f * M;
            float T1 = A - Bt;
            dist = T1 + Cref[k];
        }
        if (dist < bd || (dist == bd && k < bk)) { bd = dist; bk = k; }
    }
    {   // combine the two 8-lane candidate groups
        float bd2 = __shfl_xor(bd, 8, 64);
        int   bk2 = __shfl_xor(bk, 8, 64);
        if (bd2 < bd || (bd2 == bd && bk2 < bk)) { bd = bd2; bk = bk2; }
    }
    if (c == 0) {
        bk_l[r] = bk;
        idx_out_f[n0 + r] = (float)bk;
    }
    __syncthreads();
    {   // stage winning E rows coalesced (256B runs per row)
        int kk = bk_l[r];
        const float* er = E + (size_t)kk * DD;
        #pragma unroll
        for (int m = 0; m < 4; ++m)
            *reinterpret_cast<float4*>(&El[r][m * 64 + c * 4]) =
                *reinterpret_cast<const float4*>(er + m * 64 + c * 4);
    }
    __syncthreads();
    {   // fused output: out[b][d][hw0+rr], rr-fastest -> 2x128B segs per store
        const int rr = tid & 31;
        const int d0 = tid >> 5;                 // 0..15
        float* ob = out + (size_t)b * CHW + hw0 + rr;
        #pragma unroll
        for (int it = 0; it < 16; ++it) {
            int d = d0 + it * 16;
            float x = Xl[rr][d];
            float qv = El[rr][d];
            ob[(size_t)d * HW] = x + BETA * (qv - x);
        }
    }
}

extern "C" void kernel_launch(void* const* d_in, const int* in_sizes, int n_in,
                              void* d_out, int out_size, void* d_ws, size_t ws_size,
                              hipStream_t stream) {
    const float* lat = (const float*)d_in[0];      // (32,256,32,32) fp32
    const float* emb = (const float*)d_in[1];      // (2048,256) fp32
    float* out   = (float*)d_out;                  // 8388608 floats (output 0)
    float* idx_f = out + (size_t)BB * DD * HW;     // 32768 floats (output 1)

    // EbfT scratch in d_out (read only by k_screen, which completes before
    // k_refineout writes out). Ckey/Cref/ck in d_ws (~530 KB).
    char*  ob   = (char*)d_out;
    uint4* EbfT = (uint4*)(ob);                    // 1 MB

    char* ws = (char*)d_ws;
    float* Ckey = (float*)(ws + 0);                // 8 KB
    float* Cref = (float*)(ws + 8192);             // 8 KB
    uint2* ck   = (uint2*)(ws + 16384);            // 512 KB (2 x ushort4 per row)

    k_prep      <<<768, 256, 0, stream>>>(emb, EbfT, Cref, Ckey);
    k_screen    <<<NN / 64 * 2, 512, 0, stream>>>(lat, EbfT, Ckey, ck);
    k_refineout <<<NN / RROWS, 512, 0, stream>>>(lat, emb, Cref, ck, idx_f, out);
}

// Round 16
// 148.577 us; speedup vs baseline: 1.3205x; 1.0102x over previous
//
#include <hip/hip_runtime.h>
#include <math.h>

#define BB 32
#define DD 256
#define KK 2048
#define HW 1024
#define CHW (DD*HW)
#define NN (BB*HW)         // 32768 rows
#define BETA 0.25f
#define RROWS 32
#define NCAND 8
#define BIAS 0.125f

typedef __attribute__((ext_vector_type(8))) short short8v;   // 8 bf16 (4 VGPR)
typedef __attribute__((ext_vector_type(4))) float f32x4;

typedef const __attribute__((address_space(1))) void gv_t;
typedef __attribute__((address_space(3))) void lv_t;

__device__ __forceinline__ void gl_lds16(const void* g, void* l) {
    // LDS dest = wave-uniform base (+ lane*16 by HW); global src = per-lane addr
    __builtin_amdgcn_global_load_lds((gv_t*)g, (lv_t*)l, 16, 0, 0);
}

__device__ __forceinline__ unsigned bfr(float f) {           // fp32 -> bf16 RNE
    unsigned u = __float_as_uint(f);
    return (u + 0x7FFFu + ((u >> 16) & 1u)) >> 16;
}
__device__ __forceinline__ unsigned bfpack(float lo, float hi) {
    return bfr(lo) | (bfr(hi) << 16);
}

#define BARRIER() do { asm volatile("" ::: "memory"); \
                       __builtin_amdgcn_s_barrier();  \
                       asm volatile("" ::: "memory"); } while (0)

// ---- prep: blocks 0..255 convert E->bf16 tiled; blocks 256..767: one wave
//      per code computes np-pairwise C bitwise (r13-proven). ----
__global__ __launch_bounds__(256) void k_prep(const float* __restrict__ E,
                                              uint4* __restrict__ EbfT,
                                              float* __restrict__ Cref,
                                              float* __restrict__ Ckey) {
    int bid = blockIdx.x;
    if (bid < 256) {
        int u = bid * 256 + threadIdx.x;                 // 0..65535
        int code = u & 63, kc = (u >> 6) & 3, c = (u >> 8) & 7, t = u >> 11;
        int k = t * 64 + code;
        const float* s = E + ((size_t)k * DD + c * 32 + kc * 8);
        float4 f0 = *reinterpret_cast<const float4*>(s);
        float4 f1 = *reinterpret_cast<const float4*>(s + 4);
        uint4 o;
        o.x = bfpack(f0.x, f0.y); o.y = bfpack(f0.z, f0.w);
        o.z = bfpack(f1.x, f1.y); o.w = bfpack(f1.z, f1.w);
        EbfT[u] = o;
    } else {
        const int w = threadIdx.x >> 6;                  // 4 waves/block
        const int lane = threadIdx.x & 63;
        const int k = (bid - 256) * 4 + w;               // one code per wave
        float racc = 0.0f;
        if (lane < 16) {
#pragma clang fp contract(off)
            const int j = lane & 7, h = lane >> 3;
            const float* e = E + (size_t)k * DD + h * 128 + j;
            for (int i = 0; i < 16; ++i) {
                float t = e[i * 8];
                racc += t * t;                           // mul then add, seq
            }
        }
        float v0 = __shfl(racc, 0, 64),  v1 = __shfl(racc, 1, 64);
        float v2 = __shfl(racc, 2, 64),  v3 = __shfl(racc, 3, 64);
        float v4 = __shfl(racc, 4, 64),  v5 = __shfl(racc, 5, 64);
        float v6 = __shfl(racc, 6, 64),  v7 = __shfl(racc, 7, 64);
        float v8 = __shfl(racc, 8, 64),  v9 = __shfl(racc, 9, 64);
        float va = __shfl(racc, 10, 64), vb = __shfl(racc, 11, 64);
        float vc = __shfl(racc, 12, 64), vd = __shfl(racc, 13, 64);
        float ve = __shfl(racc, 14, 64), vf = __shfl(racc, 15, 64);
        if (lane == 0) {
#pragma clang fp contract(off)
            float lo = ((v0 + v1) + (v2 + v3)) + ((v4 + v5) + (v6 + v7));
            float hi = ((v8 + v9) + (va + vb)) + ((vc + vd) + (ve + vf));
            float res = lo + hi;
            Cref[k] = res;
            Ckey[k] = res + BIAS;
        }
    }
}

// ---- MFMA screen (r11-exact, FROZEN): 512 thr = 8 waves (4 row-grp x 16 rows,
//      2 code-grp), 64 rows/block, K-split x2 (16 tiles/block), grid 1024.
//      A = 32 VGPR in regs; E LDS dbuf + counted vmcnt(4). PROVEN 82 us. ----
__global__ __launch_bounds__(512, 4) void k_screen(
        const float* __restrict__ X, const uint4* __restrict__ EbfT,
        const float* __restrict__ Ckey, uint2* __restrict__ ck)
{
    __shared__ __align__(1024) char lds[69632];   // 2x32KB E dbuf | 4KB ckl

    const int tid = threadIdx.x;
    const int w = tid >> 6;              // 0..7
    const int rg = w >> 1;               // 0..3 row group (16 rows each)
    const int cg = w & 1;                // 0..1 code group (32 codes each)
    const int lane = tid & 63;
    const int lid = lane & 15, kc = lane >> 4;
    const int bid = blockIdx.x;
    const int half = bid & 1;
    const int tbase = half * 16;
    const int nb = (bid >> 1) * 64;
    const int b = nb >> 10;              // 64 | 1024 -> single b per block
    const int hw0 = nb & 1023;

    float* ckl = (float*)(lds + 65536);

    float ckg0 = Ckey[tbase * 64 + tid];
    float ckg1 = Ckey[tbase * 64 + 512 + tid];

    short8v a[8];                        // 16 rows x 256 d: 32 VGPR
    {
        const float* xb = X + (size_t)b * CHW + (hw0 + rg * 16 + lid);
        #pragma unroll
        for (int c = 0; c < 8; ++c) {
            const float* pp = xb + (size_t)(c * 32 + kc * 8) * HW;
            float f[8];
            #pragma unroll
            for (int j = 0; j < 8; ++j) f[j] = pp[(size_t)j * HW];
            uint4 v;
            v.x = bfpack(f[0], f[1]); v.y = bfpack(f[2], f[3]);
            v.z = bfpack(f[4], f[5]); v.w = bfpack(f[6], f[7]);
            a[c] = *reinterpret_cast<short8v*>(&v);
        }
    }
    ckl[tid] = ckg0;
    ckl[tid + 512] = ckg1;

    auto stage = [&](int t, int p) {     // t local (0..15); 8 waves x 4 x 1KB
        const uint4* src = EbfT + ((size_t)(tbase + t) * 2048 + w * 256 + lane);
        char* dst = lds + p * 32768 + (w * 256) * 16;
        #pragma unroll
        for (int i = 0; i < 4; ++i)
            gl_lds16(src + i * 64, dst + i * 1024);
    };
    stage(0, 0);
    stage(1, 1);
    asm volatile("s_waitcnt vmcnt(0) lgkmcnt(0)" ::: "memory");
    BARRIER();

    unsigned t1[2][4], t2[2][4];         // top-2 per (ct,g)
    #pragma unroll
    for (int j = 0; j < 2; ++j)
        #pragma unroll
        for (int g = 0; g < 4; ++g) { t1[j][g] = 0xFFFFFFFFu; t2[j][g] = 0xFFFFFFFFu; }

    f32x4 acc[2];
    acc[0] = (f32x4){0.f, 0.f, 0.f, 0.f};
    acc[1] = (f32x4){0.f, 0.f, 0.f, 0.f};

    int p = 0;
    float pck0 = 0.f, pck1 = 0.f;
    #pragma unroll 1
    for (int tt = 0; tt < 16; ++tt) {
        float ck0 = ckl[tt * 64 + cg * 32 + lid];
        float ck1 = ckl[tt * 64 + cg * 32 + 16 + lid];

        if (tt > 0) {
            unsigned tg = (unsigned)(tbase + tt - 1);
            #pragma unroll
            for (int ct = 0; ct < 2; ++ct) {
                float cv = ct ? pck1 : pck0;
                #pragma unroll
                for (int g = 0; g < 4; ++g) {
                    float s = fmaf(-2.0f, acc[ct][g], cv);
                    unsigned key = (__float_as_uint(s) & 0xFFFFFFE0u) | tg;
                    unsigned o1 = t1[ct][g];
                    unsigned hi = key > o1 ? key : o1;
                    t1[ct][g] = key < o1 ? key : o1;
                    t2[ct][g] = hi < t2[ct][g] ? hi : t2[ct][g];
                    acc[ct][g] = 0.0f;
                }
            }
        }
        pck0 = ck0; pck1 = ck1;

        const short8v* Ev = reinterpret_cast<const short8v*>(lds + p * 32768);
        #pragma unroll
        for (int c = 0; c < 8; ++c) {
            short8v b0 = Ev[c * 256 + kc * 64 + cg * 32 + lid];
            short8v b1 = Ev[c * 256 + kc * 64 + cg * 32 + 16 + lid];
            acc[0] = __builtin_amdgcn_mfma_f32_16x16x32_bf16(a[c], b0, acc[0], 0, 0, 0);
            acc[1] = __builtin_amdgcn_mfma_f32_16x16x32_bf16(a[c], b1, acc[1], 0, 0, 0);
        }

        BARRIER();
        if (tt < 14) {
            stage(tt + 2, p);
            asm volatile("s_waitcnt vmcnt(4)" ::: "memory");
        } else {
            asm volatile("s_waitcnt vmcnt(0)" ::: "memory");
        }
        BARRIER();
        p ^= 1;
    }
    {
        unsigned tg = (unsigned)(tbase + 15);
        #pragma unroll
        for (int ct = 0; ct < 2; ++ct) {
            float cv = ct ? pck1 : pck0;
            #pragma unroll
            for (int g = 0; g < 4; ++g) {
                float s = fmaf(-2.0f, acc[ct][g], cv);
                unsigned key = (__float_as_uint(s) & 0xFFFFFFE0u) | tg;
                unsigned o1 = t1[ct][g];
                unsigned hi = key > o1 ? key : o1;
                t1[ct][g] = key < o1 ? key : o1;
                t2[ct][g] = hi < t2[ct][g] ? hi : t2[ct][g];
            }
        }
    }

    // ---- merge: 64 slots/row x 2 keys -> top-4 of this half ----
    uint2* mb = reinterpret_cast<uint2*>(lds);            // [64 rows][64 slots] 32KB
    uint2* scr = reinterpret_cast<uint2*>(lds + 32768);   // [64][4][4] 8KB
    #pragma unroll
    for (int ct = 0; ct < 2; ++ct)
        #pragma unroll
        for (int g = 0; g < 4; ++g) {
            int row = rg * 16 + kc * 4 + g;
            int slot = cg * 32 + ct * 16 + lid;
            uint2 v; v.x = t1[ct][g]; v.y = t2[ct][g];
            mb[row * 64 + slot] = v;
        }
    BARRIER();
    if (tid < 256) {
        int row = tid >> 2, q = tid & 3;
        unsigned prev = 0; int prevj = -1;
        for (int i = 0; i < 4; ++i) {
            unsigned cur = 0xFFFFFFFFu; int curj = 0x7FFFFFFF;
            #pragma unroll
            for (int s = 0; s < 16; ++s) {
                int slot = q * 16 + ((s + tid) & 15);     // bank-spread rotation
                uint2 kv = mb[row * 64 + slot];
                int j0 = slot * 2;
                { unsigned k2=kv.x; int j=j0;   if ((k2>prev||(k2==prev&&j>prevj)) && (k2<cur||(k2==cur&&j<curj))) {cur=k2;curj=j;} }
                { unsigned k2=kv.y; int j=j0+1; if ((k2>prev||(k2==prev&&j>prevj)) && (k2<cur||(k2==cur&&j<curj))) {cur=k2;curj=j;} }
            }
            uint2 pr; pr.x = cur; pr.y = (unsigned)curj;
            scr[(row * 4 + q) * 4 + i] = pr;
            prev = cur; prevj = curj;
        }
    }
    BARRIER();
    if (tid < 64) {
        unsigned prev = 0; int prevj = -1;
        unsigned short codes[4];
        for (int i = 0; i < 4; ++i) {
            unsigned cur = 0xFFFFFFFFu; int curj = 0x7FFFFFFF;
            for (int m = 0; m < 16; ++m) {
                int mm = (m + tid) & 15;
                uint2 pr = scr[tid * 16 + mm];
                unsigned k2 = pr.x; int j = (int)pr.y;
                if ((k2>prev||(k2==prev&&j>prevj)) && (k2<cur||(k2==cur&&j<curj))) {cur=k2;curj=j;}
            }
            prev = cur; prevj = curj;
            codes[i] = (unsigned short)((cur & 31u) * 64 + (curj >> 1));  // t*64+slot
        }
        uint2 o;
        o.x = (unsigned)codes[0] | ((unsigned)codes[1] << 16);
        o.y = (unsigned)codes[2] | ((unsigned)codes[3] << 16);
        ck[(size_t)(nb + tid) * 2 + half] = o;
    }
}

// ---- refine+out v6: E-dot gather COALESCED (lane sub reads er[m*32+sub*4]
//      -> 8 lines/inst, the dwordx4 minimum, vs 64 before). f64 dot is
//      order-free so the lane repartition is numerically safe. ----
__global__ __launch_bounds__(512) void k_refineout(const float* __restrict__ X,
                                                   const float* __restrict__ E,
                                                   const float* __restrict__ Cref,
                                                   const uint2* __restrict__ ck,
                                                   float* __restrict__ idx_out_f,
                                                   float* __restrict__ out) {
    __shared__ float Xl[RROWS][DD + 4];
    __shared__ float El[RROWS][DD + 4];
    __shared__ int bk_l[RROWS];
    const int tid = threadIdx.x;
    const int n0 = blockIdx.x * RROWS;
    const int b = n0 >> 10;
    const int hw0 = n0 & 1023;
    const float* xbase = X + (size_t)b * CHW + hw0;
    #pragma unroll
    for (int it = 0; it < 16; ++it) {
        int idx = tid + it * 512;                 // 0..8191
        int d = idx >> 5, rr = idx & 31;          // 128B coalesced runs
        Xl[rr][d] = xbase[(size_t)d * HW + rr];
    }
    __syncthreads();
    const int r = tid >> 4, c = tid & 15;
    const int sub = c & 7;
    uint4 ck4 = reinterpret_cast<const uint4*>(ck)[n0 + r];   // 8 ushort codes
    const unsigned short* cs = reinterpret_cast<const unsigned short*>(&ck4);

    // ---- A = np-pairwise sum(x^2), wave-parallel bitwise emulation ----
    float A;
    {
        float racc;
        {
#pragma clang fp contract(off)
            const int j = c & 7, h = c >> 3;
            const float* xr = &Xl[r][h * 128 + j];
            racc = 0.0f;
            for (int i = 0; i < 16; ++i) {
                float t = xr[i * 8];
                racc += t * t;
            }
        }
        float w1 = __shfl_xor(racc, 1, 16);
        float s1, s2, s4;
        {
#pragma clang fp contract(off)
            s1 = racc + w1;
        }
        float w2 = __shfl_xor(s1, 2, 16);
        {
#pragma clang fp contract(off)
            s2 = s1 + w2;
        }
        float w4 = __shfl_xor(s2, 4, 16);
        {
#pragma clang fp contract(off)
            s4 = s2 + w4;                         // lo (h=0 lanes) / hi (h=1)
        }
        float w8 = __shfl_xor(s4, 8, 16);
        {
#pragma clang fp contract(off)
            A = s4 + w8;                          // lo + hi
        }
    }

    float bd = INFINITY; int bk = 0x7FFFFFFF;
    #pragma unroll
    for (int cc = 0; cc < 4; ++cc) {
        int k = cs[cc * 2 + (c >> 3)];
        const float* er = E + (size_t)k * DD;
        double p = 0.0;                          // f64: order-free proxy
        #pragma unroll
        for (int m = 0; m < 8; ++m) {
            // COALESCED: 8-lane group covers one contiguous 128B line per m
            float4 ev = *reinterpret_cast<const float4*>(er + m * 32 + sub * 4);
            float4 xv = *reinterpret_cast<const float4*>(&Xl[r][m * 32 + sub * 4]);
            p += (double)xv.x*ev.x + (double)xv.y*ev.y
               + (double)xv.z*ev.z + (double)xv.w*ev.w;
        }
        p += __shfl_xor(p, 1, 64);
        p += __shfl_xor(p, 2, 64);
        p += __shfl_xor(p, 4, 64);
        float dist;
        {
#pragma clang fp contract(off)
            float M  = (float)p;
            float Bt = 2.0f * M;
            float T1 = A - Bt;
            dist = T1 + Cref[k];
        }
        if (dist < bd || (dist == bd && k < bk)) { bd = dist; bk = k; }
    }
    {   // combine the two 8-lane candidate groups
        float bd2 = __shfl_xor(bd, 8, 64);
        int   bk2 = __shfl_xor(bk, 8, 64);
        if (bd2 < bd || (bd2 == bd && bk2 < bk)) { bd = bd2; bk = bk2; }
    }
    if (c == 0) {
        bk_l[r] = bk;
        idx_out_f[n0 + r] = (float)bk;
    }
    __syncthreads();
    {   // stage winning E rows coalesced (256B runs per row)
        int kk = bk_l[r];
        const float* er = E + (size_t)kk * DD;
        #pragma unroll
        for (int m = 0; m < 4; ++m)
            *reinterpret_cast<float4*>(&El[r][m * 64 + c * 4]) =
                *reinterpret_cast<const float4*>(er + m * 64 + c * 4);
    }
    __syncthreads();
    {   // fused output: out[b][d][hw0+rr], rr-fastest -> 2x128B segs per store
        const int rr = tid & 31;
        const int d0 = tid >> 5;                 // 0..15
        float* ob = out + (size_t)b * CHW + hw0 + rr;
        #pragma unroll
        for (int it = 0; it < 16; ++it) {
            int d = d0 + it * 16;
            float x = Xl[rr][d];
            float qv = El[rr][d];
            ob[(size_t)d * HW] = x + BETA * (qv - x);
        }
    }
}

extern "C" void kernel_launch(void* const* d_in, const int* in_sizes, int n_in,
                              void* d_out, int out_size, void* d_ws, size_t ws_size,
                              hipStream_t stream) {
    const float* lat = (const float*)d_in[0];      // (32,256,32,32) fp32
    const float* emb = (const float*)d_in[1];      // (2048,256) fp32
    float* out   = (float*)d_out;                  // 8388608 floats (output 0)
    float* idx_f = out + (size_t)BB * DD * HW;     // 32768 floats (output 1)

    // EbfT scratch in d_out (read only by k_screen, which completes before
    // k_refineout writes out). Ckey/Cref/ck in d_ws (~530 KB).
    char*  ob   = (char*)d_out;
    uint4* EbfT = (uint4*)(ob);                    // 1 MB

    char* ws = (char*)d_ws;
    float* Ckey = (float*)(ws + 0);                // 8 KB
    float* Cref = (float*)(ws + 8192);             // 8 KB
    uint2* ck   = (uint2*)(ws + 16384);            // 512 KB (2 x ushort4 per row)

    k_prep      <<<768, 256, 0, stream>>>(emb, EbfT, Cref, Ckey);
    k_screen    <<<NN / 64 * 2, 512, 0, stream>>>(lat, EbfT, Ckey, ck);
    k_refineout <<<NN / RROWS, 512, 0, stream>>>(lat, emb, Cref, ck, idx_f, out);
}

// Round 18
// 129.767 us; speedup vs baseline: 1.5119x; 1.1450x over previous
//
#include <hip/hip_runtime.h>
#include <math.h>

#define BB 32
#define DD 256
#define KK 2048
#define HW 1024
#define CHW (DD*HW)
#define NN (BB*HW)         // 32768 rows
#define BETA 0.25f
#define RROWS 32
#define NCAND 8
#define BIAS 0.125f

typedef __attribute__((ext_vector_type(8))) short short8v;   // 8 bf16 (4 VGPR)
typedef __attribute__((ext_vector_type(4))) float f32x4;

typedef const __attribute__((address_space(1))) void gv_t;
typedef __attribute__((address_space(3))) void lv_t;

__device__ __forceinline__ void gl_lds16(const void* g, void* l) {
    // LDS dest = wave-uniform base (+ lane*16 by HW); global src = per-lane addr
    __builtin_amdgcn_global_load_lds((gv_t*)g, (lv_t*)l, 16, 0, 0);
}

__device__ __forceinline__ unsigned bfr(float f) {           // fp32 -> bf16 RNE
    unsigned u = __float_as_uint(f);
    return (u + 0x7FFFu + ((u >> 16) & 1u)) >> 16;
}
__device__ __forceinline__ unsigned bfpack(float lo, float hi) {
    return bfr(lo) | (bfr(hi) << 16);
}

#define BARRIER() do { asm volatile("" ::: "memory"); \
                       __builtin_amdgcn_s_barrier();  \
                       asm volatile("" ::: "memory"); } while (0)

// ---- prep: blocks 0..255 convert E->bf16, 32-CODE tiles:
//      unit u = t*1024 + c*128 + kc*32 + code32 (t = 0..63).
//      blocks 256..767: one wave per code computes np-pairwise C (r13-proven).
__global__ __launch_bounds__(256) void k_prep(const float* __restrict__ E,
                                              uint4* __restrict__ EbfT,
                                              float* __restrict__ Cref,
                                              float* __restrict__ Ckey) {
    int bid = blockIdx.x;
    if (bid < 256) {
        int u = bid * 256 + threadIdx.x;                 // 0..65535
        int code = u & 31, kc = (u >> 5) & 3, c = (u >> 7) & 7, t = u >> 10;
        int k = t * 32 + code;
        const float* s = E + ((size_t)k * DD + c * 32 + kc * 8);
        float4 f0 = *reinterpret_cast<const float4*>(s);
        float4 f1 = *reinterpret_cast<const float4*>(s + 4);
        uint4 o;
        o.x = bfpack(f0.x, f0.y); o.y = bfpack(f0.z, f0.w);
        o.z = bfpack(f1.x, f1.y); o.w = bfpack(f1.z, f1.w);
        EbfT[u] = o;
    } else {
        const int w = threadIdx.x >> 6;                  // 4 waves/block
        const int lane = threadIdx.x & 63;
        const int k = (bid - 256) * 4 + w;               // one code per wave
        float racc = 0.0f;
        if (lane < 16) {
#pragma clang fp contract(off)
            const int j = lane & 7, h = lane >> 3;
            const float* e = E + (size_t)k * DD + h * 128 + j;
            for (int i = 0; i < 16; ++i) {
                float t = e[i * 8];
                racc += t * t;                           // mul then add, seq
            }
        }
        float v0 = __shfl(racc, 0, 64),  v1 = __shfl(racc, 1, 64);
        float v2 = __shfl(racc, 2, 64),  v3 = __shfl(racc, 3, 64);
        float v4 = __shfl(racc, 4, 64),  v5 = __shfl(racc, 5, 64);
        float v6 = __shfl(racc, 6, 64),  v7 = __shfl(racc, 7, 64);
        float v8 = __shfl(racc, 8, 64),  v9 = __shfl(racc, 9, 64);
        float va = __shfl(racc, 10, 64), vb = __shfl(racc, 11, 64);
        float vc = __shfl(racc, 12, 64), vd = __shfl(racc, 13, 64);
        float ve = __shfl(racc, 14, 64), vf = __shfl(racc, 15, 64);
        if (lane == 0) {
#pragma clang fp contract(off)
            float lo = ((v0 + v1) + (v2 + v3)) + ((v4 + v5) + (v6 + v7));
            float hi = ((v8 + v9) + (va + vb)) + ((vc + vd) + (ve + vf));
            float res = lo + hi;
            Cref[k] = res;
            Ckey[k] = res + BIAS;
        }
    }
}

// ---- MFMA screen v10b: r11 structure, 32-CODE tiles; LDS 36864 -> HW can
//      schedule 4 blocks/CU (32 waves/CU) at the measured 52-VGPR footprint.
//      Launch-bounds budget kept at the PROVEN (512,4) — the bound only sets
//      the compiler register budget, not runtime occupancy. ----
__global__ __launch_bounds__(512, 4) void k_screen(
        const float* __restrict__ X, const uint4* __restrict__ EbfT,
        const float* __restrict__ Ckey, uint2* __restrict__ ck)
{
    __shared__ __align__(1024) char lds[36864];   // 2x16KB E dbuf | 4KB ckl

    const int tid = threadIdx.x;
    const int w = tid >> 6;              // 0..7
    const int rg = w >> 1;               // 0..3 row group (16 rows each)
    const int cg = w & 1;                // 0..1 code group (16 codes each)
    const int lane = tid & 63;
    const int lid = lane & 15, kc = lane >> 4;
    const int bid = blockIdx.x;
    const int half = bid & 1;
    const int tbase = half * 32;         // 32-code tiles, 32 per half
    const int nb = (bid >> 1) * 64;
    const int b = nb >> 10;              // 64 | 1024 -> single b per block
    const int hw0 = nb & 1023;

    float* ckl = (float*)(lds + 32768);

    float ckg0 = Ckey[half * 1024 + tid];
    float ckg1 = Ckey[half * 1024 + 512 + tid];

    short8v a[8];                        // 16 rows x 256 d: 32 VGPR
    {
        const float* xb = X + (size_t)b * CHW + (hw0 + rg * 16 + lid);
        #pragma unroll
        for (int c = 0; c < 8; ++c) {
            const float* pp = xb + (size_t)(c * 32 + kc * 8) * HW;
            float f[8];
            #pragma unroll
            for (int j = 0; j < 8; ++j) f[j] = pp[(size_t)j * HW];
            uint4 v;
            v.x = bfpack(f[0], f[1]); v.y = bfpack(f[2], f[3]);
            v.z = bfpack(f[4], f[5]); v.w = bfpack(f[6], f[7]);
            a[c] = *reinterpret_cast<short8v*>(&v);
        }
    }
    ckl[tid] = ckg0;
    ckl[tid + 512] = ckg1;

    auto stage = [&](int t, int p) {     // t local (0..31); 8 waves x 2 x 1KB
        const uint4* src = EbfT + ((size_t)(tbase + t) * 1024 + w * 128 + lane);
        char* dst = lds + p * 16384 + (w * 128) * 16;
        #pragma unroll
        for (int i = 0; i < 2; ++i)
            gl_lds16(src + i * 64, dst + i * 1024);
    };
    stage(0, 0);
    stage(1, 1);
    asm volatile("s_waitcnt vmcnt(2) lgkmcnt(0)" ::: "memory");   // tile0 + ckl
    BARRIER();

    unsigned t1[4], t2[4];               // top-2 per g
    #pragma unroll
    for (int g = 0; g < 4; ++g) { t1[g] = 0xFFFFFFFFu; t2[g] = 0xFFFFFFFFu; }

    f32x4 acc = (f32x4){0.f, 0.f, 0.f, 0.f};

    int p = 0;
    float pck = 0.f;
    #pragma unroll 1
    for (int tt = 0; tt < 32; ++tt) {
        float ckv = ckl[tt * 32 + cg * 16 + lid];

        // selection for tile tt-1 (register-only, overlaps ds_read latency)
        if (tt > 0) {
            unsigned tg = (unsigned)(tt - 1);          // local tile, 5 bits
            #pragma unroll
            for (int g = 0; g < 4; ++g) {
                float s = fmaf(-2.0f, acc[g], pck);
                unsigned key = (__float_as_uint(s) & 0xFFFFFFE0u) | tg;
                unsigned o1 = t1[g];
                unsigned hi = key > o1 ? key : o1;
                t1[g] = key < o1 ? key : o1;
                t2[g] = hi < t2[g] ? hi : t2[g];
                acc[g] = 0.0f;
            }
        }
        pck = ckv;

        const short8v* Ev = reinterpret_cast<const short8v*>(lds + p * 16384);
        #pragma unroll
        for (int c = 0; c < 8; ++c) {
            short8v b0 = Ev[c * 128 + kc * 32 + cg * 16 + lid];
            acc = __builtin_amdgcn_mfma_f32_16x16x32_bf16(a[c], b0, acc, 0, 0, 0);
        }

        BARRIER();
        if (tt < 30) {
            stage(tt + 2, p);
            asm volatile("s_waitcnt vmcnt(2)" ::: "memory");   // tile tt+1 ready
        } else {
            asm volatile("s_waitcnt vmcnt(0)" ::: "memory");
        }
        BARRIER();
        p ^= 1;
    }
    {
        unsigned tg = 31u;
        #pragma unroll
        for (int g = 0; g < 4; ++g) {
            float s = fmaf(-2.0f, acc[g], pck);
            unsigned key = (__float_as_uint(s) & 0xFFFFFFE0u) | tg;
            unsigned o1 = t1[g];
            unsigned hi = key > o1 ? key : o1;
            t1[g] = key < o1 ? key : o1;
            t2[g] = hi < t2[g] ? hi : t2[g];
        }
    }

    // ---- merge: 32 slots/row x 2 keys -> top-4 of this half ----
    uint2* mb = reinterpret_cast<uint2*>(lds);            // [64 rows][32 slots] 16KB
    uint2* scr = reinterpret_cast<uint2*>(lds + 16384);   // [64][4][4] 8KB
    #pragma unroll
    for (int g = 0; g < 4; ++g) {
        int row = rg * 16 + kc * 4 + g;
        int slot = cg * 16 + lid;
        uint2 v; v.x = t1[g]; v.y = t2[g];
        mb[row * 32 + slot] = v;
    }
    BARRIER();
    if (tid < 256) {
        int row = tid >> 2, q = tid & 3;
        unsigned prev = 0; int prevj = -1;
        for (int i = 0; i < 4; ++i) {
            unsigned cur = 0xFFFFFFFFu; int curj = 0x7FFFFFFF;
            #pragma unroll
            for (int s = 0; s < 8; ++s) {
                int slot = q * 8 + ((s + tid) & 7);       // bank-spread rotation
                uint2 kv = mb[row * 32 + slot];
                int j0 = slot * 2;
                { unsigned k2=kv.x; int j=j0;   if ((k2>prev||(k2==prev&&j>prevj)) && (k2<cur||(k2==cur&&j<curj))) {cur=k2;curj=j;} }
                { unsigned k2=kv.y; int j=j0+1; if ((k2>prev||(k2==prev&&j>prevj)) && (k2<cur||(k2==cur&&j<curj))) {cur=k2;curj=j;} }
            }
            uint2 pr; pr.x = cur; pr.y = (unsigned)curj;
            scr[(row * 4 + q) * 4 + i] = pr;
            prev = cur; prevj = curj;
        }
    }
    BARRIER();
    if (tid < 64) {
        unsigned prev = 0; int prevj = -1;
        unsigned short codes[4];
        for (int i = 0; i < 4; ++i) {
            unsigned cur = 0xFFFFFFFFu; int curj = 0x7FFFFFFF;
            for (int m = 0; m < 16; ++m) {
                int mm = (m + tid) & 15;
                uint2 pr = scr[tid * 16 + mm];
                unsigned k2 = pr.x; int j = (int)pr.y;
                if ((k2>prev||(k2==prev&&j>prevj)) && (k2<cur||(k2==cur&&j<curj))) {cur=k2;curj=j;}
            }
            prev = cur; prevj = curj;
            // k = half*1024 + local_tile*32 + slot
            codes[i] = (unsigned short)(half * 1024 + (int)(cur & 31u) * 32 + ((curj >> 1) & 31));
        }
        uint2 o;
        o.x = (unsigned)codes[0] | ((unsigned)codes[1] << 16);
        o.y = (unsigned)codes[2] | ((unsigned)codes[3] << 16);
        ck[(size_t)(nb + tid) * 2 + half] = o;
    }
}

// ---- refine+out v6 (r16-proven, FROZEN except k-mask insurance) ----
__global__ __launch_bounds__(512) void k_refineout(const float* __restrict__ X,
                                                   const float* __restrict__ E,
                                                   const float* __restrict__ Cref,
                                                   const uint2* __restrict__ ck,
                                                   float* __restrict__ idx_out_f,
                                                   float* __restrict__ out) {
    __shared__ float Xl[RROWS][DD + 4];
    __shared__ float El[RROWS][DD + 4];
    __shared__ int bk_l[RROWS];
    const int tid = threadIdx.x;
    const int n0 = blockIdx.x * RROWS;
    const int b = n0 >> 10;
    const int hw0 = n0 & 1023;
    const float* xbase = X + (size_t)b * CHW + hw0;
    #pragma unroll
    for (int it = 0; it < 16; ++it) {
        int idx = tid + it * 512;                 // 0..8191
        int d = idx >> 5, rr = idx & 31;          // 128B coalesced runs
        Xl[rr][d] = xbase[(size_t)d * HW + rr];
    }
    __syncthreads();
    const int r = tid >> 4, c = tid & 15;
    const int sub = c & 7;
    uint4 ck4 = reinterpret_cast<const uint4*>(ck)[n0 + r];   // 8 ushort codes
    const unsigned short* cs = reinterpret_cast<const unsigned short*>(&ck4);

    // ---- A = np-pairwise sum(x^2), wave-parallel bitwise emulation ----
    float A;
    {
        float racc;
        {
#pragma clang fp contract(off)
            const int j = c & 7, h = c >> 3;
            const float* xr = &Xl[r][h * 128 + j];
            racc = 0.0f;
            for (int i = 0; i < 16; ++i) {
                float t = xr[i * 8];
                racc += t * t;
            }
        }
        float w1 = __shfl_xor(racc, 1, 16);
        float s1, s2, s4;
        {
#pragma clang fp contract(off)
            s1 = racc + w1;
        }
        float w2 = __shfl_xor(s1, 2, 16);
        {
#pragma clang fp contract(off)
            s2 = s1 + w2;
        }
        float w4 = __shfl_xor(s2, 4, 16);
        {
#pragma clang fp contract(off)
            s4 = s2 + w4;                         // lo (h=0 lanes) / hi (h=1)
        }
        float w8 = __shfl_xor(s4, 8, 16);
        {
#pragma clang fp contract(off)
            A = s4 + w8;                          // lo + hi
        }
    }

    float bd = INFINITY; int bk = 0x7FFFFFFF;
    #pragma unroll
    for (int cc = 0; cc < 4; ++cc) {
        int k = cs[cc * 2 + (c >> 3)] & 2047;    // insurance: legit codes <=2047
        const float* er = E + (size_t)k * DD;
        double p = 0.0;                          // f64: order-free proxy
        #pragma unroll
        for (int m = 0; m < 8; ++m) {
            // COALESCED: 8-lane group covers one contiguous 128B line per m
            float4 ev = *reinterpret_cast<const float4*>(er + m * 32 + sub * 4);
            float4 xv = *reinterpret_cast<const float4*>(&Xl[r][m * 32 + sub * 4]);
            p += (double)xv.x*ev.x + (double)xv.y*ev.y
               + (double)xv.z*ev.z + (double)xv.w*ev.w;
        }
        p += __shfl_xor(p, 1, 64);
        p += __shfl_xor(p, 2, 64);
        p += __shfl_xor(p, 4, 64);
        float dist;
        {
#pragma clang fp contract(off)
            float M  = (float)p;
            float Bt = 2.0f * M;
            float T1 = A - Bt;
            dist = T1 + Cref[k];
        }
        if (dist < bd || (dist == bd && k < bk)) { bd = dist; bk = k; }
    }
    {   // combine the two 8-lane candidate groups
        float bd2 = __shfl_xor(bd, 8, 64);
        int   bk2 = __shfl_xor(bk, 8, 64);
        if (bd2 < bd || (bd2 == bd && bk2 < bk)) { bd = bd2; bk = bk2; }
    }
    if (c == 0) {
        bk_l[r] = bk;
        idx_out_f[n0 + r] = (float)bk;
    }
    __syncthreads();
    {   // stage winning E rows coalesced (256B runs per row)
        int kk = bk_l[r];
        const float* er = E + (size_t)kk * DD;
        #pragma unroll
        for (int m = 0; m < 4; ++m)
            *reinterpret_cast<float4*>(&El[r][m * 64 + c * 4]) =
                *reinterpret_cast<const float4*>(er + m * 64 + c * 4);
    }
    __syncthreads();
    {   // fused output: out[b][d][hw0+rr], rr-fastest -> 2x128B segs per store
        const int rr = tid & 31;
        const int d0 = tid >> 5;                 // 0..15
        float* ob = out + (size_t)b * CHW + hw0 + rr;
        #pragma unroll
        for (int it = 0; it < 16; ++it) {
            int d = d0 + it * 16;
            float x = Xl[rr][d];
            float qv = El[rr][d];
            ob[(size_t)d * HW] = x + BETA * (qv - x);
        }
    }
}

extern "C" void kernel_launch(void* const* d_in, const int* in_sizes, int n_in,
                              void* d_out, int out_size, void* d_ws, size_t ws_size,
                              hipStream_t stream) {
    const float* lat = (const float*)d_in[0];      // (32,256,32,32) fp32
    const float* emb = (const float*)d_in[1];      // (2048,256) fp32
    float* out   = (float*)d_out;                  // 8388608 floats (output 0)
    float* idx_f = out + (size_t)BB * DD * HW;     // 32768 floats (output 1)

    // EbfT scratch in d_out (read only by k_screen, which completes before
    // k_refineout writes out). Ckey/Cref/ck in d_ws (~530 KB).
    char*  ob   = (char*)d_out;
    uint4* EbfT = (uint4*)(ob);                    // 1 MB

    char* ws = (char*)d_ws;
    float* Ckey = (float*)(ws + 0);                // 8 KB
    float* Cref = (float*)(ws + 8192);             // 8 KB
    uint2* ck   = (uint2*)(ws + 16384);            // 512 KB (2 x ushort4 per row)

    k_prep      <<<768, 256, 0, stream>>>(emb, EbfT, Cref, Ckey);
    k_screen    <<<NN / 64 * 2, 512, 0, stream>>>(lat, EbfT, Ckey, ck);
    k_refineout <<<NN / RROWS, 512, 0, stream>>>(lat, emb, Cref, ck, idx_f, out);
}